// Round 20
// baseline (117.487 us; speedup 1.0000x reference)
//
#include <hip/hip_runtime.h>
#include <hip/hip_fp16.h>

#define N_NODES 100000
#define N_EDGES 1000000
#define D_FEAT  64

// Binning: 64 consecutive dst nodes per bin
#define BIN_SHIFT 6
#define BIN_NODES 64
#define NBINS ((N_NODES + BIN_NODES - 1) >> BIN_SHIFT)   // 1563
#define BIN_CAP 1152    // bin total ~Poisson(640), 20 sigma headroom

// Dense single-pass partition: 256 chunks (R19 structure)
#define NCHUNK 256
#define CHUNK_E ((N_EDGES + NCHUNK - 1) / NCHUNK)   // 3907
#define PCHUNK 3968                                  // padded region (ints)

// Feature sharding: 8 slices of 8 features (16B fp16) each; slice s is a
// contiguous 1.6MB region -> L2-resident per XCD when slice == blockIdx&7.
#define NSLICE 8
#define SLICE_INTS (N_NODES * 4)        // 400000 ints = 1.6MB per slice
#define SLICE_BYTES (N_NODES * 16)

// ---------------------------------------------------------------------------
// Workspace layout (ints):
//   PFCNT  u32 [NCHUNK][NBINS]  (prefix<<16)|count            (1.6 MB)
//   bucket [NCHUNK][PCHUNK]     packed (local_dst<<17)|src    (4.1 MB)
//   emb16s [NSLICE][N_NODES][16B]  fp16 feature slices        (12.8 MB)
// ---------------------------------------------------------------------------
#define WS_PFCNT  0
#define WS_BUCKET (NCHUNK * NBINS)
#define WS_EMB16  (WS_BUCKET + NCHUNK * PCHUNK)
#define WS_NEEDED ((size_t)(WS_EMB16 + NSLICE * SLICE_INTS) * sizeof(int))

// K1: every block partitions its chunk (LDS hist -> scan -> dense place),
// then converts its share of emb f32 -> fp16 slices. All 256 CUs busy.
__global__ __launch_bounds__(1024) void prep_kernel(const float* __restrict__ emb,
                                                    const int* __restrict__ src,
                                                    const int* __restrict__ dst,
                                                    int* __restrict__ ws) {
    __shared__ int h[NBINS];                 // hist -> prefix -> cursor
    int tid = threadIdx.x;
    int c   = blockIdx.x;
    for (int j = tid; j < NBINS; j += 1024) h[j] = 0;
    __syncthreads();

    int e0 = c * CHUNK_E, e1 = min(N_EDGES, e0 + CHUNK_E);
    // pass A: histogram dst bins (LDS atomics)
    for (int e = e0 + tid; e < e1; e += 1024)
        atomicAdd(&h[dst[e] >> BIN_SHIFT], 1);
    __syncthreads();

    // save this thread's counts before the in-place scan (<=2 bins/thread)
    int j0 = tid, j1 = tid + 1024;
    int c0 = (j0 < NBINS) ? h[j0] : 0;
    int c1 = (j1 < NBINS) ? h[j1] : 0;
    __syncthreads();

    // wave 0: exclusive scan of h in place
    if (tid < 64) {
        int lane = tid, carry = 0;
        for (int cb = 0; cb < NBINS; cb += 64) {
            int idx = cb + lane;
            int v = (idx < NBINS) ? h[idx] : 0;
            int incl = v;
            #pragma unroll
            for (int o = 1; o < 64; o <<= 1) {
                int t = __shfl_up(incl, o);
                if (lane >= o) incl += t;
            }
            if (idx < NBINS) h[idx] = carry + incl - v;
            carry += __shfl(incl, 63);
        }
    }
    __syncthreads();

    // write packed (prefix<<16)|count — one contiguous 6.2 KB row
    int* __restrict__ pfcnt = ws + WS_PFCNT + c * NBINS;
    if (j0 < NBINS) pfcnt[j0] = (h[j0] << 16) | c0;
    if (j1 < NBINS) pfcnt[j1] = (h[j1] << 16) | c1;

    // pass B: re-read edges (L2-hot), place into dense region; h = cursors
    int* __restrict__ run = ws + WS_BUCKET + c * PCHUNK;
    for (int e = e0 + tid; e < e1; e += 1024) {
        int d = dst[e], s = src[e];
        int slot = atomicAdd(&h[d >> BIN_SHIFT], 1);
        run[slot] = ((d & (BIN_NODES - 1)) << 17) | s;
    }

    // conversion into transposed slices: chunk k = (node n, feat-block f);
    // read 32B (8 floats) coalesced, write 16B (8 halves) to slice f.
    {
        int* __restrict__ e16 = ws + WS_EMB16;
        const float4* __restrict__ e32 = (const float4*)emb;
        const int CHUNKS = N_NODES * NSLICE / NCHUNK;    // 3125
        int k0 = c * CHUNKS;
        for (int k = k0 + tid; k < k0 + CHUNKS; k += 1024) {
            int n = k >> 3, f = k & 7;
            float4 v0 = e32[n * 16 + f * 2];
            float4 v1 = e32[n * 16 + f * 2 + 1];
            __half2 h0 = __floats2half2_rn(v0.x, v0.y);
            __half2 h1 = __floats2half2_rn(v0.z, v0.w);
            __half2 h2 = __floats2half2_rn(v1.x, v1.y);
            __half2 h3 = __floats2half2_rn(v1.z, v1.w);
            uint4 u;
            u.x = *(unsigned*)&h0; u.y = *(unsigned*)&h1;
            u.z = *(unsigned*)&h2; u.w = *(unsigned*)&h3;
            *(uint4*)(e16 + f * SLICE_INTS + n * 4) = u;
        }
    }
}

// K2: block = (bin, slice); slice = blockIdx&7 -> XCD-affine so each XCD's
// random reads hit its own L2-resident 1.6MB slice. Stage + counting-sort
// as before (replicated x8, LDS-cheap); gather: wave = 8 nodes x 8 edge
// slots, lane loads 16B (8 halves) -> f32, 3-step shfl_xor reduce, lane 0
// of each group writes 32B of the output row.
__global__ __launch_bounds__(512) void fused_gather_kernel(const int* __restrict__ ws,
                                                           float* __restrict__ out) {
    __shared__ int s_edges[BIN_CAP];
    __shared__ int s_sorted[BIN_CAP];
    __shared__ int s_rcnt[NCHUNK];
    __shared__ int s_roff[NCHUNK];
    __shared__ int s_rbase[NCHUNK];
    __shared__ int s_hist[BIN_NODES];
    __shared__ int s_off[BIN_NODES];
    __shared__ int s_cur[BIN_NODES];
    __shared__ int s_alloc;

    int b     = blockIdx.x >> 3;
    int slice = blockIdx.x & 7;
    int tid   = threadIdx.x;
    const char* __restrict__ sl =
        (const char*)(ws + WS_EMB16) + (size_t)slice * SLICE_BYTES;

    if (tid < BIN_NODES) s_hist[tid] = 0;
    if (tid == 0) s_alloc = 0;
    __syncthreads();

    // phase 1: threads 0..255 read packed prefix|count (L2-resident array)
    if (tid < NCHUNK) {
        unsigned pc = (unsigned)ws[WS_PFCNT + tid * NBINS + b];
        int cnt = (int)(pc & 0xFFFFu);
        int pf  = (int)(pc >> 16);
        s_rcnt[tid]  = cnt;
        s_rbase[tid] = tid * PCHUNK + pf;
        s_roff[tid]  = atomicAdd(&s_alloc, cnt);
    }
    __syncthreads();
    int total = s_alloc;
    if (total > BIN_CAP) total = BIN_CAP;

    // phase 2: 2 threads per run copy entries + histogram
    {
        int g = tid >> 1, li = tid & 1;
        int cg = s_rcnt[g], og = s_roff[g];
        const int* __restrict__ run = ws + WS_BUCKET + s_rbase[g];
        for (int i = li; i < cg; i += 2) {
            int o = og + i;
            if (o < BIN_CAP) {
                int p = run[i];
                s_edges[o] = p;
                atomicAdd(&s_hist[p >> 17], 1);
            }
        }
    }
    __syncthreads();

    // scan 64 hist entries with wave 0
    if (tid < 64) {
        int v = s_hist[tid];
        int incl = v;
        #pragma unroll
        for (int o = 1; o < 64; o <<= 1) {
            int t = __shfl_up(incl, o);
            if (tid >= o) incl += t;
        }
        s_off[tid] = incl - v;
        s_cur[tid] = incl - v;
    }
    __syncthreads();

    // counting-sort scatter within LDS
    for (int i = tid; i < total; i += 512) {
        int p = s_edges[i];
        s_sorted[atomicAdd(&s_cur[p >> 17], 1)] = p & 0x1FFFF;
    }
    __syncthreads();

    // gather: 8 waves; wave covers 8 nodes x 8 edge-slots
    int wave = tid >> 6, lane = tid & 63;
    int ln   = wave * 8 + (lane >> 3);   // local node 0..63
    int es   = lane & 7;                 // edge slot
    int deg  = s_hist[ln];
    int off  = s_off[ln];

    float4 aLo = make_float4(0.f, 0.f, 0.f, 0.f);
    float4 aHi = make_float4(0.f, 0.f, 0.f, 0.f);

    int i = es;
    // main: 2 L2-hit loads in flight per lane (deg > 8+es)
    for (; i + 8 < deg; i += 16) {
        uint4 u0 = *(const uint4*)(sl + (size_t)s_sorted[off + i]     * 16);
        uint4 u1 = *(const uint4*)(sl + (size_t)s_sorted[off + i + 8] * 16);
        float2 f;
        f = __half22float2(*(__half2*)&u0.x); aLo.x += f.x; aLo.y += f.y;
        f = __half22float2(*(__half2*)&u0.y); aLo.z += f.x; aLo.w += f.y;
        f = __half22float2(*(__half2*)&u0.z); aHi.x += f.x; aHi.y += f.y;
        f = __half22float2(*(__half2*)&u0.w); aHi.z += f.x; aHi.w += f.y;
        f = __half22float2(*(__half2*)&u1.x); aLo.x += f.x; aLo.y += f.y;
        f = __half22float2(*(__half2*)&u1.y); aLo.z += f.x; aLo.w += f.y;
        f = __half22float2(*(__half2*)&u1.z); aHi.x += f.x; aHi.y += f.y;
        f = __half22float2(*(__half2*)&u1.w); aHi.z += f.x; aHi.w += f.y;
    }
    if (i < deg) {
        uint4 u0 = *(const uint4*)(sl + (size_t)s_sorted[off + i] * 16);
        float2 f;
        f = __half22float2(*(__half2*)&u0.x); aLo.x += f.x; aLo.y += f.y;
        f = __half22float2(*(__half2*)&u0.y); aLo.z += f.x; aLo.w += f.y;
        f = __half22float2(*(__half2*)&u0.z); aHi.x += f.x; aHi.y += f.y;
        f = __half22float2(*(__half2*)&u0.w); aHi.z += f.x; aHi.w += f.y;
    }

    // reduce across the 8 edge slots (low 3 lane bits)
    #pragma unroll
    for (int m = 1; m < 8; m <<= 1) {
        aLo.x += __shfl_xor(aLo.x, m);
        aLo.y += __shfl_xor(aLo.y, m);
        aLo.z += __shfl_xor(aLo.z, m);
        aLo.w += __shfl_xor(aLo.w, m);
        aHi.x += __shfl_xor(aHi.x, m);
        aHi.y += __shfl_xor(aHi.y, m);
        aHi.z += __shfl_xor(aHi.z, m);
        aHi.w += __shfl_xor(aHi.w, m);
    }

    if (es == 0) {
        int node = (b << BIN_SHIFT) + ln;
        if (node < N_NODES) {
            float inv = 1.0f / (float)max(deg, 1);
            aLo.x *= inv; aLo.y *= inv; aLo.z *= inv; aLo.w *= inv;
            aHi.x *= inv; aHi.y *= inv; aHi.z *= inv; aHi.w *= inv;
            float* orow = out + (size_t)node * D_FEAT + slice * 8;
            *(float4*)(orow)     = aLo;
            *(float4*)(orow + 4) = aHi;
        }
    }
}

// ======================= Fallback (R1 atomic path) =========================

__global__ void gcn_zero_kernel(float* __restrict__ out, float* __restrict__ counts) {
    int stride = gridDim.x * blockDim.x;
    int i = blockIdx.x * blockDim.x + threadIdx.x;
    const int total = N_NODES * D_FEAT;
    for (int idx = i; idx < total; idx += stride) out[idx] = 0.0f;
    for (int idx = i; idx < N_NODES; idx += stride) counts[idx] = 0.0f;
}

__global__ void gcn_scatter_kernel(const float* __restrict__ emb,
                                   const int* __restrict__ src,
                                   const int* __restrict__ dst,
                                   float* __restrict__ out,
                                   float* __restrict__ counts) {
    int gid  = blockIdx.x * blockDim.x + threadIdx.x;
    int edge = gid >> 6;
    int lane = gid & 63;
    if (edge >= N_EDGES) return;
    int s = src[edge];
    int d = dst[edge];
    float v = emb[(size_t)s * D_FEAT + lane];
    atomicAdd(&out[(size_t)d * D_FEAT + lane], v);
    if (lane == 0) atomicAdd(&counts[d], 1.0f);
}

__global__ void gcn_norm_kernel(float* __restrict__ out,
                                const float* __restrict__ counts) {
    int i = blockIdx.x * blockDim.x + threadIdx.x;
    if (i >= N_NODES * D_FEAT) return;
    int n = i >> 6;
    float c = counts[n];
    out[i] *= (1.0f / fmaxf(c, 1.0f));
}

// ===========================================================================

extern "C" void kernel_launch(void* const* d_in, const int* in_sizes, int n_in,
                              void* d_out, int out_size, void* d_ws, size_t ws_size,
                              hipStream_t stream) {
    const float* emb = (const float*)d_in[0];
    const int*   src = (const int*)d_in[1];
    const int*   dst = (const int*)d_in[2];
    float* out = (float*)d_out;

    if (ws_size >= WS_NEEDED) {
        int* ws = (int*)d_ws;
        prep_kernel<<<NCHUNK, 1024, 0, stream>>>(emb, src, dst, ws);
        fused_gather_kernel<<<NBINS * NSLICE, 512, 0, stream>>>(ws, out);
    } else {
        float* counts = (float*)d_ws;
        gcn_zero_kernel<<<2048, 256, 0, stream>>>(out, counts);
        const int scatter_blocks = (N_EDGES * 64) / 256;
        gcn_scatter_kernel<<<scatter_blocks, 256, 0, stream>>>(emb, src, dst, out, counts);
        const int norm_blocks = (N_NODES * D_FEAT + 255) / 256;
        gcn_norm_kernel<<<norm_blocks, 256, 0, stream>>>(out, counts);
    }
}

// Round 21
// 85.592 us; speedup vs baseline: 1.3726x; 1.3726x over previous
//
#include <hip/hip_runtime.h>
#include <hip/hip_fp16.h>

#define N_NODES 100000
#define N_EDGES 1000000
#define D_FEAT  64

// Binning: 64 consecutive dst nodes per bin
#define BIN_SHIFT 6
#define BIN_NODES 64
#define NBINS ((N_NODES + BIN_NODES - 1) >> BIN_SHIFT)   // 1563
#define BIN_CAP 1152    // bin total ~Poisson(640), 20 sigma headroom

// Dense single-pass partition: 256 chunks (R19 structure)
#define NCHUNK 256
#define CHUNK_E ((N_EDGES + NCHUNK - 1) / NCHUNK)   // 3907
#define PCHUNK 3968                                  // padded region (ints)

// Feature sharding: 8 slices of 8 features (16B fp16) each; slice s is a
// contiguous 1.6MB region -> L2-resident per XCD when slice == blockIdx&7.
#define NSLICE 8
#define SLICE_INTS (N_NODES * 4)        // 400000 ints = 1.6MB per slice
#define SLICE_BYTES (N_NODES * 16)

// ---------------------------------------------------------------------------
// Workspace layout (ints):
//   PFCNT  u32 [NCHUNK][NBINS]  (prefix<<16)|count            (1.6 MB)
//   bucket [NCHUNK][PCHUNK]     packed (local_dst<<17)|src    (4.1 MB)
//   emb16s [NSLICE][N_NODES][16B]  fp16 feature slices        (12.8 MB)
//   sorted [NBINS][BIN_CAP]     src ids grouped by node       (7.2 MB)
//   meta   [NBINS][64]          (off<<16)|deg per node        (0.4 MB)
// ---------------------------------------------------------------------------
#define WS_PFCNT  0
#define WS_BUCKET (NCHUNK * NBINS)
#define WS_EMB16  (WS_BUCKET + NCHUNK * PCHUNK)
#define WS_SORTED (WS_EMB16 + NSLICE * SLICE_INTS)
#define WS_META   (WS_SORTED + NBINS * BIN_CAP)
#define WS_NEEDED ((size_t)(WS_META + NBINS * BIN_NODES) * sizeof(int))

// K1: every block partitions its chunk (LDS hist -> scan -> dense place),
// then converts its share of emb f32 -> fp16 slices. All 256 CUs busy.
__global__ __launch_bounds__(1024) void prep_kernel(const float* __restrict__ emb,
                                                    const int* __restrict__ src,
                                                    const int* __restrict__ dst,
                                                    int* __restrict__ ws) {
    __shared__ int h[NBINS];                 // hist -> prefix -> cursor
    int tid = threadIdx.x;
    int c   = blockIdx.x;
    for (int j = tid; j < NBINS; j += 1024) h[j] = 0;
    __syncthreads();

    int e0 = c * CHUNK_E, e1 = min(N_EDGES, e0 + CHUNK_E);
    for (int e = e0 + tid; e < e1; e += 1024)
        atomicAdd(&h[dst[e] >> BIN_SHIFT], 1);
    __syncthreads();

    int j0 = tid, j1 = tid + 1024;
    int c0 = (j0 < NBINS) ? h[j0] : 0;
    int c1 = (j1 < NBINS) ? h[j1] : 0;
    __syncthreads();

    if (tid < 64) {
        int lane = tid, carry = 0;
        for (int cb = 0; cb < NBINS; cb += 64) {
            int idx = cb + lane;
            int v = (idx < NBINS) ? h[idx] : 0;
            int incl = v;
            #pragma unroll
            for (int o = 1; o < 64; o <<= 1) {
                int t = __shfl_up(incl, o);
                if (lane >= o) incl += t;
            }
            if (idx < NBINS) h[idx] = carry + incl - v;
            carry += __shfl(incl, 63);
        }
    }
    __syncthreads();

    int* __restrict__ pfcnt = ws + WS_PFCNT + c * NBINS;
    if (j0 < NBINS) pfcnt[j0] = (h[j0] << 16) | c0;
    if (j1 < NBINS) pfcnt[j1] = (h[j1] << 16) | c1;

    int* __restrict__ run = ws + WS_BUCKET + c * PCHUNK;
    for (int e = e0 + tid; e < e1; e += 1024) {
        int d = dst[e], s = src[e];
        int slot = atomicAdd(&h[d >> BIN_SHIFT], 1);
        run[slot] = ((d & (BIN_NODES - 1)) << 17) | s;
    }

    // conversion into transposed slices
    {
        int* __restrict__ e16 = ws + WS_EMB16;
        const float4* __restrict__ e32 = (const float4*)emb;
        const int CHUNKS = N_NODES * NSLICE / NCHUNK;    // 3125
        int k0 = c * CHUNKS;
        for (int k = k0 + tid; k < k0 + CHUNKS; k += 1024) {
            int n = k >> 3, f = k & 7;
            float4 v0 = e32[n * 16 + f * 2];
            float4 v1 = e32[n * 16 + f * 2 + 1];
            __half2 h0 = __floats2half2_rn(v0.x, v0.y);
            __half2 h1 = __floats2half2_rn(v0.z, v0.w);
            __half2 h2 = __floats2half2_rn(v1.x, v1.y);
            __half2 h3 = __floats2half2_rn(v1.z, v1.w);
            uint4 u;
            u.x = *(unsigned*)&h0; u.y = *(unsigned*)&h1;
            u.z = *(unsigned*)&h2; u.w = *(unsigned*)&h3;
            *(uint4*)(e16 + f * SLICE_INTS + n * 4) = u;
        }
    }
}

// K2: per-bin sort (R19's stage + counting-sort), results to global:
// sorted src list + packed (off<<16)|deg meta. Done ONCE per bin.
__global__ __launch_bounds__(512) void sort_kernel(const int* __restrict__ ws_c,
                                                   int* __restrict__ ws) {
    __shared__ int s_edges[BIN_CAP];
    __shared__ int s_rcnt[NCHUNK];
    __shared__ int s_roff[NCHUNK];
    __shared__ int s_rbase[NCHUNK];
    __shared__ int s_hist[BIN_NODES];
    __shared__ int s_off[BIN_NODES];
    __shared__ int s_cur[BIN_NODES];
    __shared__ int s_alloc;

    int b   = blockIdx.x;
    int tid = threadIdx.x;

    if (tid < BIN_NODES) s_hist[tid] = 0;
    if (tid == 0) s_alloc = 0;
    __syncthreads();

    if (tid < NCHUNK) {
        unsigned pc = (unsigned)ws_c[WS_PFCNT + tid * NBINS + b];
        int cnt = (int)(pc & 0xFFFFu);
        int pf  = (int)(pc >> 16);
        s_rcnt[tid]  = cnt;
        s_rbase[tid] = tid * PCHUNK + pf;
        s_roff[tid]  = atomicAdd(&s_alloc, cnt);
    }
    __syncthreads();
    int total = s_alloc;
    if (total > BIN_CAP) total = BIN_CAP;

    {
        int g = tid >> 1, li = tid & 1;
        int cg = s_rcnt[g], og = s_roff[g];
        const int* __restrict__ run = ws_c + WS_BUCKET + s_rbase[g];
        for (int i = li; i < cg; i += 2) {
            int o = og + i;
            if (o < BIN_CAP) {
                int p = run[i];
                s_edges[o] = p;
                atomicAdd(&s_hist[p >> 17], 1);
            }
        }
    }
    __syncthreads();

    if (tid < 64) {
        int v = s_hist[tid];
        int incl = v;
        #pragma unroll
        for (int o = 1; o < 64; o <<= 1) {
            int t = __shfl_up(incl, o);
            if (tid >= o) incl += t;
        }
        s_off[tid] = incl - v;
        s_cur[tid] = incl - v;
        ws[WS_META + b * BIN_NODES + tid] = ((incl - v) << 16) | v;
    }
    __syncthreads();

    // counting-sort scatter directly to GLOBAL sorted array (L2-write)
    int* __restrict__ sorted = ws + WS_SORTED + b * BIN_CAP;
    for (int i = tid; i < total; i += 512) {
        int p = s_edges[i];
        sorted[atomicAdd(&s_cur[p >> 17], 1)] = p & 0x1FFFF;
    }
}

// K3: block = (bin, slice); slice = blockIdx&7 -> XCD-affine L2-resident
// slice. No sort: read meta + sorted list (dense), gather, reduce, write.
__global__ __launch_bounds__(512) void slice_gather_kernel(const int* __restrict__ ws,
                                                           float* __restrict__ out) {
    __shared__ int s_sorted[BIN_CAP];
    __shared__ int s_meta[BIN_NODES];

    int b     = blockIdx.x >> 3;
    int slice = blockIdx.x & 7;
    int tid   = threadIdx.x;
    const char* __restrict__ sl =
        (const char*)(ws + WS_EMB16) + (size_t)slice * SLICE_BYTES;

    if (tid < BIN_NODES) s_meta[tid] = ws[WS_META + b * BIN_NODES + tid];
    __syncthreads();
    int mlast = s_meta[BIN_NODES - 1];
    int total = (mlast >> 16) + (mlast & 0xFFFF);
    if (total > BIN_CAP) total = BIN_CAP;

    const int* __restrict__ sorted = ws + WS_SORTED + b * BIN_CAP;
    for (int i = tid; i < total; i += 512) s_sorted[i] = sorted[i];
    __syncthreads();

    // gather: 8 waves; wave covers 8 nodes x 8 edge-slots
    int wave = tid >> 6, lane = tid & 63;
    int ln   = wave * 8 + (lane >> 3);   // local node 0..63
    int es   = lane & 7;                 // edge slot
    int m    = s_meta[ln];
    int deg  = m & 0xFFFF;
    int off  = m >> 16;

    float4 aLo = make_float4(0.f, 0.f, 0.f, 0.f);
    float4 aHi = make_float4(0.f, 0.f, 0.f, 0.f);

    int i = es;
    for (; i + 8 < deg; i += 16) {
        uint4 u0 = *(const uint4*)(sl + (size_t)s_sorted[off + i]     * 16);
        uint4 u1 = *(const uint4*)(sl + (size_t)s_sorted[off + i + 8] * 16);
        float2 f;
        f = __half22float2(*(__half2*)&u0.x); aLo.x += f.x; aLo.y += f.y;
        f = __half22float2(*(__half2*)&u0.y); aLo.z += f.x; aLo.w += f.y;
        f = __half22float2(*(__half2*)&u0.z); aHi.x += f.x; aHi.y += f.y;
        f = __half22float2(*(__half2*)&u0.w); aHi.z += f.x; aHi.w += f.y;
        f = __half22float2(*(__half2*)&u1.x); aLo.x += f.x; aLo.y += f.y;
        f = __half22float2(*(__half2*)&u1.y); aLo.z += f.x; aLo.w += f.y;
        f = __half22float2(*(__half2*)&u1.z); aHi.x += f.x; aHi.y += f.y;
        f = __half22float2(*(__half2*)&u1.w); aHi.z += f.x; aHi.w += f.y;
    }
    if (i < deg) {
        uint4 u0 = *(const uint4*)(sl + (size_t)s_sorted[off + i] * 16);
        float2 f;
        f = __half22float2(*(__half2*)&u0.x); aLo.x += f.x; aLo.y += f.y;
        f = __half22float2(*(__half2*)&u0.y); aLo.z += f.x; aLo.w += f.y;
        f = __half22float2(*(__half2*)&u0.z); aHi.x += f.x; aHi.y += f.y;
        f = __half22float2(*(__half2*)&u0.w); aHi.z += f.x; aHi.w += f.y;
    }

    // reduce across the 8 edge slots (low 3 lane bits)
    #pragma unroll
    for (int m2 = 1; m2 < 8; m2 <<= 1) {
        aLo.x += __shfl_xor(aLo.x, m2);
        aLo.y += __shfl_xor(aLo.y, m2);
        aLo.z += __shfl_xor(aLo.z, m2);
        aLo.w += __shfl_xor(aLo.w, m2);
        aHi.x += __shfl_xor(aHi.x, m2);
        aHi.y += __shfl_xor(aHi.y, m2);
        aHi.z += __shfl_xor(aHi.z, m2);
        aHi.w += __shfl_xor(aHi.w, m2);
    }

    if (es == 0) {
        int node = (b << BIN_SHIFT) + ln;
        if (node < N_NODES) {
            float inv = 1.0f / (float)max(deg, 1);
            aLo.x *= inv; aLo.y *= inv; aLo.z *= inv; aLo.w *= inv;
            aHi.x *= inv; aHi.y *= inv; aHi.z *= inv; aHi.w *= inv;
            float* orow = out + (size_t)node * D_FEAT + slice * 8;
            *(float4*)(orow)     = aLo;
            *(float4*)(orow + 4) = aHi;
        }
    }
}

// ======================= Fallback (R1 atomic path) =========================

__global__ void gcn_zero_kernel(float* __restrict__ out, float* __restrict__ counts) {
    int stride = gridDim.x * blockDim.x;
    int i = blockIdx.x * blockDim.x + threadIdx.x;
    const int total = N_NODES * D_FEAT;
    for (int idx = i; idx < total; idx += stride) out[idx] = 0.0f;
    for (int idx = i; idx < N_NODES; idx += stride) counts[idx] = 0.0f;
}

__global__ void gcn_scatter_kernel(const float* __restrict__ emb,
                                   const int* __restrict__ src,
                                   const int* __restrict__ dst,
                                   float* __restrict__ out,
                                   float* __restrict__ counts) {
    int gid  = blockIdx.x * blockDim.x + threadIdx.x;
    int edge = gid >> 6;
    int lane = gid & 63;
    if (edge >= N_EDGES) return;
    int s = src[edge];
    int d = dst[edge];
    float v = emb[(size_t)s * D_FEAT + lane];
    atomicAdd(&out[(size_t)d * D_FEAT + lane], v);
    if (lane == 0) atomicAdd(&counts[d], 1.0f);
}

__global__ void gcn_norm_kernel(float* __restrict__ out,
                                const float* __restrict__ counts) {
    int i = blockIdx.x * blockDim.x + threadIdx.x;
    if (i >= N_NODES * D_FEAT) return;
    int n = i >> 6;
    float c = counts[n];
    out[i] *= (1.0f / fmaxf(c, 1.0f));
}

// ===========================================================================

extern "C" void kernel_launch(void* const* d_in, const int* in_sizes, int n_in,
                              void* d_out, int out_size, void* d_ws, size_t ws_size,
                              hipStream_t stream) {
    const float* emb = (const float*)d_in[0];
    const int*   src = (const int*)d_in[1];
    const int*   dst = (const int*)d_in[2];
    float* out = (float*)d_out;

    if (ws_size >= WS_NEEDED) {
        int* ws = (int*)d_ws;
        prep_kernel<<<NCHUNK, 1024, 0, stream>>>(emb, src, dst, ws);
        sort_kernel<<<NBINS, 512, 0, stream>>>(ws, ws);
        slice_gather_kernel<<<NBINS * NSLICE, 512, 0, stream>>>(ws, out);
    } else {
        float* counts = (float*)d_ws;
        gcn_zero_kernel<<<2048, 256, 0, stream>>>(out, counts);
        const int scatter_blocks = (N_EDGES * 64) / 256;
        gcn_scatter_kernel<<<scatter_blocks, 256, 0, stream>>>(emb, src, dst, out, counts);
        const int norm_blocks = (N_NODES * D_FEAT + 255) / 256;
        gcn_norm_kernel<<<norm_blocks, 256, 0, stream>>>(out, counts);
    }
}

// Round 22
// 80.010 us; speedup vs baseline: 1.4684x; 1.0698x over previous
//
#include <hip/hip_runtime.h>
#include <hip/hip_fp16.h>

#define N_NODES 100000
#define N_EDGES 1000000
#define D_FEAT  64

// Binning: 64 consecutive dst nodes per bin
#define BIN_SHIFT 6
#define BIN_NODES 64
#define NBINS ((N_NODES + BIN_NODES - 1) >> BIN_SHIFT)   // 1563
#define BIN_CAP 1152    // bin total ~Poisson(640), 20 sigma headroom

// Dense single-pass partition: 256 chunks (R19 structure)
#define NCHUNK 256
#define CHUNK_E ((N_EDGES + NCHUNK - 1) / NCHUNK)   // 3907
#define PCHUNK 3968                                  // padded region (ints)

// Feature sharding: 8 slices of 8 features (16B fp16) each; slice s is a
// contiguous 1.6MB region -> L2-resident per XCD when slice == blockIdx&7.
#define NSLICE 8
#define SLICE_INTS (N_NODES * 4)        // 400000 ints = 1.6MB per slice
#define SLICE_BYTES (N_NODES * 16)

// ---------------------------------------------------------------------------
// Workspace layout (ints):
//   PFCNT  u32 [NCHUNK][NBINS]  (prefix<<16)|count            (1.6 MB)
//   bucket [NCHUNK][PCHUNK]     packed (local_dst<<17)|src    (4.1 MB)
//   emb16s [NSLICE][N_NODES][16B]  fp16 feature slices        (12.8 MB)
//   sorted [NBINS][BIN_CAP]     src ids grouped by node       (7.2 MB)
//   meta   [NBINS][64]          (off<<16)|deg per node        (0.4 MB)
// ---------------------------------------------------------------------------
#define WS_PFCNT  0
#define WS_BUCKET (NCHUNK * NBINS)
#define WS_EMB16  (WS_BUCKET + NCHUNK * PCHUNK)
#define WS_SORTED (WS_EMB16 + NSLICE * SLICE_INTS)
#define WS_META   (WS_SORTED + NBINS * BIN_CAP)
#define WS_NEEDED ((size_t)(WS_META + NBINS * BIN_NODES) * sizeof(int))

// K1: every block partitions its chunk (LDS hist -> scan -> dense place),
// then converts its share of emb f32 -> fp16 slices. All 256 CUs busy.
__global__ __launch_bounds__(1024) void prep_kernel(const float* __restrict__ emb,
                                                    const int* __restrict__ src,
                                                    const int* __restrict__ dst,
                                                    int* __restrict__ ws) {
    __shared__ int h[NBINS];                 // hist -> prefix -> cursor
    int tid = threadIdx.x;
    int c   = blockIdx.x;
    for (int j = tid; j < NBINS; j += 1024) h[j] = 0;
    __syncthreads();

    int e0 = c * CHUNK_E, e1 = min(N_EDGES, e0 + CHUNK_E);
    for (int e = e0 + tid; e < e1; e += 1024)
        atomicAdd(&h[dst[e] >> BIN_SHIFT], 1);
    __syncthreads();

    int j0 = tid, j1 = tid + 1024;
    int c0 = (j0 < NBINS) ? h[j0] : 0;
    int c1 = (j1 < NBINS) ? h[j1] : 0;
    __syncthreads();

    if (tid < 64) {
        int lane = tid, carry = 0;
        for (int cb = 0; cb < NBINS; cb += 64) {
            int idx = cb + lane;
            int v = (idx < NBINS) ? h[idx] : 0;
            int incl = v;
            #pragma unroll
            for (int o = 1; o < 64; o <<= 1) {
                int t = __shfl_up(incl, o);
                if (lane >= o) incl += t;
            }
            if (idx < NBINS) h[idx] = carry + incl - v;
            carry += __shfl(incl, 63);
        }
    }
    __syncthreads();

    int* __restrict__ pfcnt = ws + WS_PFCNT + c * NBINS;
    if (j0 < NBINS) pfcnt[j0] = (h[j0] << 16) | c0;
    if (j1 < NBINS) pfcnt[j1] = (h[j1] << 16) | c1;

    int* __restrict__ run = ws + WS_BUCKET + c * PCHUNK;
    for (int e = e0 + tid; e < e1; e += 1024) {
        int d = dst[e], s = src[e];
        int slot = atomicAdd(&h[d >> BIN_SHIFT], 1);
        run[slot] = ((d & (BIN_NODES - 1)) << 17) | s;
    }

    // conversion into transposed slices
    {
        int* __restrict__ e16 = ws + WS_EMB16;
        const float4* __restrict__ e32 = (const float4*)emb;
        const int CHUNKS = N_NODES * NSLICE / NCHUNK;    // 3125
        int k0 = c * CHUNKS;
        for (int k = k0 + tid; k < k0 + CHUNKS; k += 1024) {
            int n = k >> 3, f = k & 7;
            float4 v0 = e32[n * 16 + f * 2];
            float4 v1 = e32[n * 16 + f * 2 + 1];
            __half2 h0 = __floats2half2_rn(v0.x, v0.y);
            __half2 h1 = __floats2half2_rn(v0.z, v0.w);
            __half2 h2 = __floats2half2_rn(v1.x, v1.y);
            __half2 h3 = __floats2half2_rn(v1.z, v1.w);
            uint4 u;
            u.x = *(unsigned*)&h0; u.y = *(unsigned*)&h1;
            u.z = *(unsigned*)&h2; u.w = *(unsigned*)&h3;
            *(uint4*)(e16 + f * SLICE_INTS + n * 4) = u;
        }
    }
}

// K2: per-bin sort (stage + counting-sort), results to global:
// sorted src list + packed (off<<16)|deg meta. Done ONCE per bin.
__global__ __launch_bounds__(512) void sort_kernel(const int* __restrict__ ws_c,
                                                   int* __restrict__ ws) {
    __shared__ int s_edges[BIN_CAP];
    __shared__ int s_rcnt[NCHUNK];
    __shared__ int s_roff[NCHUNK];
    __shared__ int s_rbase[NCHUNK];
    __shared__ int s_hist[BIN_NODES];
    __shared__ int s_cur[BIN_NODES];
    __shared__ int s_alloc;

    int b   = blockIdx.x;
    int tid = threadIdx.x;

    if (tid < BIN_NODES) s_hist[tid] = 0;
    if (tid == 0) s_alloc = 0;
    __syncthreads();

    if (tid < NCHUNK) {
        unsigned pc = (unsigned)ws_c[WS_PFCNT + tid * NBINS + b];
        int cnt = (int)(pc & 0xFFFFu);
        int pf  = (int)(pc >> 16);
        s_rcnt[tid]  = cnt;
        s_rbase[tid] = tid * PCHUNK + pf;
        s_roff[tid]  = atomicAdd(&s_alloc, cnt);
    }
    __syncthreads();
    int total = s_alloc;
    if (total > BIN_CAP) total = BIN_CAP;

    {
        int g = tid >> 1, li = tid & 1;
        int cg = s_rcnt[g], og = s_roff[g];
        const int* __restrict__ run = ws_c + WS_BUCKET + s_rbase[g];
        for (int i = li; i < cg; i += 2) {
            int o = og + i;
            if (o < BIN_CAP) {
                int p = run[i];
                s_edges[o] = p;
                atomicAdd(&s_hist[p >> 17], 1);
            }
        }
    }
    __syncthreads();

    if (tid < 64) {
        int v = s_hist[tid];
        int incl = v;
        #pragma unroll
        for (int o = 1; o < 64; o <<= 1) {
            int t = __shfl_up(incl, o);
            if (tid >= o) incl += t;
        }
        s_cur[tid] = incl - v;
        ws[WS_META + b * BIN_NODES + tid] = ((incl - v) << 16) | v;
    }
    __syncthreads();

    // counting-sort scatter directly to GLOBAL sorted array (L2-write)
    int* __restrict__ sorted = ws + WS_SORTED + b * BIN_CAP;
    for (int i = tid; i < total; i += 512) {
        int p = s_edges[i];
        sorted[atomicAdd(&s_cur[p >> 17], 1)] = p & 0x1FFFF;
    }
}

// K3: block = (bin, slice); slice = blockIdx&7 -> XCD-affine L2-resident
// slice. NO LDS, NO barriers: thread = (node, edge-slot); meta read is a
// coalesced broadcast; sorted list read direct from global (L2/L3-cached,
// dense); 2-deep pipeline (next index fetched during current row load).
__global__ __launch_bounds__(512) void slice_gather_kernel(const int* __restrict__ ws,
                                                           float* __restrict__ out) {
    int b     = blockIdx.x >> 3;
    int slice = blockIdx.x & 7;
    int tid   = threadIdx.x;
    const char* __restrict__ sl =
        (const char*)(ws + WS_EMB16) + (size_t)slice * SLICE_BYTES;

    int ln = tid >> 3;                   // local node 0..63
    int es = tid & 7;                    // edge slot 0..7
    int m  = ws[WS_META + b * BIN_NODES + ln];
    int deg = m & 0xFFFF;
    int off = m >> 16;
    const int* __restrict__ sorted = ws + WS_SORTED + b * BIN_CAP;

    float4 aLo = make_float4(0.f, 0.f, 0.f, 0.f);
    float4 aHi = make_float4(0.f, 0.f, 0.f, 0.f);

    int i = es;
    if (i < deg) {
        int s0 = sorted[off + i];
        for (; i + 8 < deg; i += 8) {
            int s1 = sorted[off + i + 8];          // prefetch next index
            uint4 u = *(const uint4*)(sl + (size_t)s0 * 16);
            float2 f;
            f = __half22float2(*(__half2*)&u.x); aLo.x += f.x; aLo.y += f.y;
            f = __half22float2(*(__half2*)&u.y); aLo.z += f.x; aLo.w += f.y;
            f = __half22float2(*(__half2*)&u.z); aHi.x += f.x; aHi.y += f.y;
            f = __half22float2(*(__half2*)&u.w); aHi.z += f.x; aHi.w += f.y;
            s0 = s1;
        }
        uint4 u = *(const uint4*)(sl + (size_t)s0 * 16);
        float2 f;
        f = __half22float2(*(__half2*)&u.x); aLo.x += f.x; aLo.y += f.y;
        f = __half22float2(*(__half2*)&u.y); aLo.z += f.x; aLo.w += f.y;
        f = __half22float2(*(__half2*)&u.z); aHi.x += f.x; aHi.y += f.y;
        f = __half22float2(*(__half2*)&u.w); aHi.z += f.x; aHi.w += f.y;
    }

    // reduce across the 8 edge slots (low 3 lane bits)
    #pragma unroll
    for (int m2 = 1; m2 < 8; m2 <<= 1) {
        aLo.x += __shfl_xor(aLo.x, m2);
        aLo.y += __shfl_xor(aLo.y, m2);
        aLo.z += __shfl_xor(aLo.z, m2);
        aLo.w += __shfl_xor(aLo.w, m2);
        aHi.x += __shfl_xor(aHi.x, m2);
        aHi.y += __shfl_xor(aHi.y, m2);
        aHi.z += __shfl_xor(aHi.z, m2);
        aHi.w += __shfl_xor(aHi.w, m2);
    }

    if (es == 0) {
        int node = (b << BIN_SHIFT) + ln;
        if (node < N_NODES) {
            float inv = 1.0f / (float)max(deg, 1);
            aLo.x *= inv; aLo.y *= inv; aLo.z *= inv; aLo.w *= inv;
            aHi.x *= inv; aHi.y *= inv; aHi.z *= inv; aHi.w *= inv;
            float* orow = out + (size_t)node * D_FEAT + slice * 8;
            *(float4*)(orow)     = aLo;
            *(float4*)(orow + 4) = aHi;
        }
    }
}

// ======================= Fallback (R1 atomic path) =========================

__global__ void gcn_zero_kernel(float* __restrict__ out, float* __restrict__ counts) {
    int stride = gridDim.x * blockDim.x;
    int i = blockIdx.x * blockDim.x + threadIdx.x;
    const int total = N_NODES * D_FEAT;
    for (int idx = i; idx < total; idx += stride) out[idx] = 0.0f;
    for (int idx = i; idx < N_NODES; idx += stride) counts[idx] = 0.0f;
}

__global__ void gcn_scatter_kernel(const float* __restrict__ emb,
                                   const int* __restrict__ src,
                                   const int* __restrict__ dst,
                                   float* __restrict__ out,
                                   float* __restrict__ counts) {
    int gid  = blockIdx.x * blockDim.x + threadIdx.x;
    int edge = gid >> 6;
    int lane = gid & 63;
    if (edge >= N_EDGES) return;
    int s = src[edge];
    int d = dst[edge];
    float v = emb[(size_t)s * D_FEAT + lane];
    atomicAdd(&out[(size_t)d * D_FEAT + lane], v);
    if (lane == 0) atomicAdd(&counts[d], 1.0f);
}

__global__ void gcn_norm_kernel(float* __restrict__ out,
                                const float* __restrict__ counts) {
    int i = blockIdx.x * blockDim.x + threadIdx.x;
    if (i >= N_NODES * D_FEAT) return;
    int n = i >> 6;
    float c = counts[n];
    out[i] *= (1.0f / fmaxf(c, 1.0f));
}

// ===========================================================================

extern "C" void kernel_launch(void* const* d_in, const int* in_sizes, int n_in,
                              void* d_out, int out_size, void* d_ws, size_t ws_size,
                              hipStream_t stream) {
    const float* emb = (const float*)d_in[0];
    const int*   src = (const int*)d_in[1];
    const int*   dst = (const int*)d_in[2];
    float* out = (float*)d_out;

    if (ws_size >= WS_NEEDED) {
        int* ws = (int*)d_ws;
        prep_kernel<<<NCHUNK, 1024, 0, stream>>>(emb, src, dst, ws);
        sort_kernel<<<NBINS, 512, 0, stream>>>(ws, ws);
        slice_gather_kernel<<<NBINS * NSLICE, 512, 0, stream>>>(ws, out);
    } else {
        float* counts = (float*)d_ws;
        gcn_zero_kernel<<<2048, 256, 0, stream>>>(out, counts);
        const int scatter_blocks = (N_EDGES * 64) / 256;
        gcn_scatter_kernel<<<scatter_blocks, 256, 0, stream>>>(emb, src, dst, out, counts);
        const int norm_blocks = (N_NODES * D_FEAT + 255) / 256;
        gcn_norm_kernel<<<norm_blocks, 256, 0, stream>>>(out, counts);
    }
}

// Round 23
// 54.057 us; speedup vs baseline: 2.1734x; 1.4801x over previous
//
#include <hip/hip_runtime.h>
#include <hip/hip_fp16.h>

#define N_NODES 100000
#define N_EDGES 1000000
#define D_FEAT  64

// Binning: 64 consecutive dst nodes per bin
#define BIN_SHIFT 6
#define BIN_NODES 64
#define NBINS ((N_NODES + BIN_NODES - 1) >> BIN_SHIFT)   // 1563
#define BIN_CAP 1152    // bin total ~Poisson(640), 20 sigma headroom

// Single-pass chunked partition: 128 chunks, fixed per-(chunk,bin) cells.
// Cell = 24 ints: [0]=count, [1..23]=packed entries. lambda = 5 per cell;
// P(Poisson(5) >= 24) ~ 1e-12 -> overflow never happens.
#define NCHUNK 128
#define CHUNK_E ((N_EDGES + NCHUNK - 1) / NCHUNK)   // 7813
#define CELL 24
#define CCAP_E 23

// ---------------------------------------------------------------------------
// Workspace layout (ints):
//   bucket [NCHUNK][NBINS][CELL]   ~19.2 MB
//   emb16  [N_NODES*D_FEAT] __half ~12.8 MB (3.2M ints)
// ---------------------------------------------------------------------------
#define WS_BUCKET_INTS ((size_t)NCHUNK * NBINS * CELL)
#define WS_EMB16       WS_BUCKET_INTS
#define WS_NEEDED      ((WS_BUCKET_INTS + (size_t)N_NODES * D_FEAT / 2) * sizeof(int))

// K1 (fused): blocks 0..127 partition edges into cells; blocks 128..255
// convert emb f32 -> fp16 (streams on otherwise-idle CUs, overlapped).
__global__ __launch_bounds__(1024) void prep_kernel(const float* __restrict__ emb,
                                                    const int* __restrict__ src,
                                                    const int* __restrict__ dst,
                                                    int* __restrict__ ws) {
    int tid = threadIdx.x;
    if (blockIdx.x < NCHUNK) {
        __shared__ int h[NBINS];
        for (int j = tid; j < NBINS; j += 1024) h[j] = 0;
        __syncthreads();
        int c  = blockIdx.x;
        int e0 = c * CHUNK_E, e1 = min(N_EDGES, e0 + CHUNK_E);
        int* __restrict__ cells = ws + (size_t)c * NBINS * CELL;
        for (int e = e0 + tid; e < e1; e += 1024) {
            int d = dst[e], s = src[e];
            int bin = d >> BIN_SHIFT;
            int slot = atomicAdd(&h[bin], 1);            // LDS atomic
            if (slot < CCAP_E)
                cells[bin * CELL + 1 + slot] = ((d & (BIN_NODES - 1)) << 17) | s;
        }
        __syncthreads();
        for (int j = tid; j < NBINS; j += 1024)
            cells[j * CELL] = min(h[j], CCAP_E);
    } else {
        // f32 -> fp16 conversion: 1.6M float4 -> uint2(4 halves)
        __half2* __restrict__ e16 = (__half2*)(ws + WS_EMB16);
        const float4* __restrict__ e32 = (const float4*)emb;
        const int total4 = N_NODES * D_FEAT / 4;         // 1,600,000
        int start = (blockIdx.x - NCHUNK) * 1024 + tid;
        for (int i = start; i < total4; i += NCHUNK * 1024) {
            float4 v = e32[i];
            e16[2 * i]     = __floats2half2_rn(v.x, v.y);
            e16[2 * i + 1] = __floats2half2_rn(v.z, v.w);
        }
    }
}

// K2: per-bin gather (fp16 rows). Stage the bin's 128 cells into LDS via a
// bump allocator (+histogram), counting-sort by local dst, then gather:
// 8 waves x 8 nodes in pairs; 16-lane group per row, lane loads 8B (4
// halves) -> f32 accumulate; shfl_xor reduce across 4 edge subgroups.
__global__ __launch_bounds__(512) void fused_gather_kernel(const int* __restrict__ ws,
                                                           float* __restrict__ out) {
    __shared__ int s_edges[BIN_CAP];
    __shared__ int s_sorted[BIN_CAP];
    __shared__ int s_rcnt[NCHUNK];
    __shared__ int s_roff[NCHUNK];
    __shared__ int s_hist[BIN_NODES];
    __shared__ int s_off[BIN_NODES];
    __shared__ int s_cur[BIN_NODES];
    __shared__ int s_alloc;

    const char* __restrict__ emb16 = (const char*)(ws + WS_EMB16);
    int b   = blockIdx.x;
    int tid = threadIdx.x;

    if (tid < BIN_NODES) s_hist[tid] = 0;
    if (tid == 0) s_alloc = 0;
    __syncthreads();

    // phase 1: threads 0..127 read their cell's count, bump-allocate
    if (tid < NCHUNK) {
        int cnt = ws[((size_t)tid * NBINS + b) * CELL];
        s_rcnt[tid] = cnt;
        s_roff[tid] = atomicAdd(&s_alloc, cnt);
    }
    __syncthreads();
    int total = s_alloc;
    if (total > BIN_CAP) total = BIN_CAP;

    // phase 2: 4 threads per cell copy entries + histogram
    {
        int g = tid >> 2, li = tid & 3;
        int cg = s_rcnt[g], og = s_roff[g];
        const int* __restrict__ cell = ws + ((size_t)g * NBINS + b) * CELL + 1;
        for (int i = li; i < cg; i += 4) {
            int o = og + i;
            if (o < BIN_CAP) {
                int p = cell[i];
                s_edges[o] = p;
                atomicAdd(&s_hist[p >> 17], 1);
            }
        }
    }
    __syncthreads();

    // scan 64 hist entries with wave 0
    if (tid < 64) {
        int v = s_hist[tid];
        int incl = v;
        #pragma unroll
        for (int o = 1; o < 64; o <<= 1) {
            int t = __shfl_up(incl, o);
            if (tid >= o) incl += t;
        }
        s_off[tid] = incl - v;
        s_cur[tid] = incl - v;
    }
    __syncthreads();

    // counting-sort scatter within LDS
    for (int i = tid; i < total; i += 512) {
        int p = s_edges[i];
        s_sorted[atomicAdd(&s_cur[p >> 17], 1)] = p & 0x1FFFF;
    }
    __syncthreads();

    // gather: 8 waves x 8 nodes in 4 pairs; sub = edge slot, fq = 8B index
    int wave = tid >> 6, lane = tid & 63;
    int sub  = lane >> 4;
    int fq   = lane & 15;
    const int fb = fq << 3;          // byte offset of this lane's 8B in a row

    #pragma unroll
    for (int pr = 0; pr < 4; ++pr) {
        int lnA = wave * 8 + pr * 2;
        int lnB = lnA + 1;
        int degA = s_hist[lnA], offA = s_off[lnA];
        int degB = s_hist[lnB], offB = s_off[lnB];

        float4 accA = make_float4(0.f, 0.f, 0.f, 0.f);
        float4 accB = make_float4(0.f, 0.f, 0.f, 0.f);

        int iA = sub, iB = sub;
        // main loops (deg > 15; rare): 4 rows in flight
        for (; iA + 12 < degA; iA += 16) {
            uint2 u0 = *(const uint2*)(emb16 + ((size_t)s_sorted[offA + iA]      << 7) + fb);
            uint2 u1 = *(const uint2*)(emb16 + ((size_t)s_sorted[offA + iA + 4]  << 7) + fb);
            uint2 u2 = *(const uint2*)(emb16 + ((size_t)s_sorted[offA + iA + 8]  << 7) + fb);
            uint2 u3 = *(const uint2*)(emb16 + ((size_t)s_sorted[offA + iA + 12] << 7) + fb);
            float2 f;
            f = __half22float2(*(__half2*)&u0.x); accA.x += f.x; accA.y += f.y;
            f = __half22float2(*(__half2*)&u0.y); accA.z += f.x; accA.w += f.y;
            f = __half22float2(*(__half2*)&u1.x); accA.x += f.x; accA.y += f.y;
            f = __half22float2(*(__half2*)&u1.y); accA.z += f.x; accA.w += f.y;
            f = __half22float2(*(__half2*)&u2.x); accA.x += f.x; accA.y += f.y;
            f = __half22float2(*(__half2*)&u2.y); accA.z += f.x; accA.w += f.y;
            f = __half22float2(*(__half2*)&u3.x); accA.x += f.x; accA.y += f.y;
            f = __half22float2(*(__half2*)&u3.y); accA.z += f.x; accA.w += f.y;
        }
        for (; iB + 12 < degB; iB += 16) {
            uint2 u0 = *(const uint2*)(emb16 + ((size_t)s_sorted[offB + iB]      << 7) + fb);
            uint2 u1 = *(const uint2*)(emb16 + ((size_t)s_sorted[offB + iB + 4]  << 7) + fb);
            uint2 u2 = *(const uint2*)(emb16 + ((size_t)s_sorted[offB + iB + 8]  << 7) + fb);
            uint2 u3 = *(const uint2*)(emb16 + ((size_t)s_sorted[offB + iB + 12] << 7) + fb);
            float2 f;
            f = __half22float2(*(__half2*)&u0.x); accB.x += f.x; accB.y += f.y;
            f = __half22float2(*(__half2*)&u0.y); accB.z += f.x; accB.w += f.y;
            f = __half22float2(*(__half2*)&u1.x); accB.x += f.x; accB.y += f.y;
            f = __half22float2(*(__half2*)&u1.y); accB.z += f.x; accB.w += f.y;
            f = __half22float2(*(__half2*)&u2.x); accB.x += f.x; accB.y += f.y;
            f = __half22float2(*(__half2*)&u2.y); accB.z += f.x; accB.w += f.y;
            f = __half22float2(*(__half2*)&u3.x); accB.x += f.x; accB.y += f.y;
            f = __half22float2(*(__half2*)&u3.y); accB.z += f.x; accB.w += f.y;
        }
        // tails: up to 6 independent guarded loads, all issued before use
        // (uint2{0,0} decodes to half zeros -> adds 0)
        {
            uint2 a0 = make_uint2(0u, 0u), a1 = a0, a2 = a0;
            uint2 b0 = a0, b1 = a0, b2 = a0;
            if (iA < degA)     a0 = *(const uint2*)(emb16 + ((size_t)s_sorted[offA + iA]     << 7) + fb);
            if (iA + 4 < degA) a1 = *(const uint2*)(emb16 + ((size_t)s_sorted[offA + iA + 4] << 7) + fb);
            if (iA + 8 < degA) a2 = *(const uint2*)(emb16 + ((size_t)s_sorted[offA + iA + 8] << 7) + fb);
            if (iB < degB)     b0 = *(const uint2*)(emb16 + ((size_t)s_sorted[offB + iB]     << 7) + fb);
            if (iB + 4 < degB) b1 = *(const uint2*)(emb16 + ((size_t)s_sorted[offB + iB + 4] << 7) + fb);
            if (iB + 8 < degB) b2 = *(const uint2*)(emb16 + ((size_t)s_sorted[offB + iB + 8] << 7) + fb);
            float2 f;
            f = __half22float2(*(__half2*)&a0.x); accA.x += f.x; accA.y += f.y;
            f = __half22float2(*(__half2*)&a0.y); accA.z += f.x; accA.w += f.y;
            f = __half22float2(*(__half2*)&a1.x); accA.x += f.x; accA.y += f.y;
            f = __half22float2(*(__half2*)&a1.y); accA.z += f.x; accA.w += f.y;
            f = __half22float2(*(__half2*)&a2.x); accA.x += f.x; accA.y += f.y;
            f = __half22float2(*(__half2*)&a2.y); accA.z += f.x; accA.w += f.y;
            f = __half22float2(*(__half2*)&b0.x); accB.x += f.x; accB.y += f.y;
            f = __half22float2(*(__half2*)&b0.y); accB.z += f.x; accB.w += f.y;
            f = __half22float2(*(__half2*)&b1.x); accB.x += f.x; accB.y += f.y;
            f = __half22float2(*(__half2*)&b1.y); accB.z += f.x; accB.w += f.y;
            f = __half22float2(*(__half2*)&b2.x); accB.x += f.x; accB.y += f.y;
            f = __half22float2(*(__half2*)&b2.y); accB.z += f.x; accB.w += f.y;
        }

        // reduce both across the 4 edge subgroups (independent chains)
        #pragma unroll
        for (int m = 16; m < 64; m <<= 1) {
            accA.x += __shfl_xor(accA.x, m);  accB.x += __shfl_xor(accB.x, m);
            accA.y += __shfl_xor(accA.y, m);  accB.y += __shfl_xor(accB.y, m);
            accA.z += __shfl_xor(accA.z, m);  accB.z += __shfl_xor(accB.z, m);
            accA.w += __shfl_xor(accA.w, m);  accB.w += __shfl_xor(accB.w, m);
        }

        if (sub == 0) {
            int nodeA = (b << BIN_SHIFT) + lnA;
            int nodeB = (b << BIN_SHIFT) + lnB;
            float invA = 1.0f / (float)max(degA, 1);
            float invB = 1.0f / (float)max(degB, 1);
            accA.x *= invA; accA.y *= invA; accA.z *= invA; accA.w *= invA;
            accB.x *= invB; accB.y *= invB; accB.z *= invB; accB.w *= invB;
            if (nodeA < N_NODES)
                *(float4*)(out + (size_t)nodeA * D_FEAT + fq * 4) = accA;
            if (nodeB < N_NODES)
                *(float4*)(out + (size_t)nodeB * D_FEAT + fq * 4) = accB;
        }
    }
}

// ======================= Fallback (R1 atomic path) =========================

__global__ void gcn_zero_kernel(float* __restrict__ out, float* __restrict__ counts) {
    int stride = gridDim.x * blockDim.x;
    int i = blockIdx.x * blockDim.x + threadIdx.x;
    const int total = N_NODES * D_FEAT;
    for (int idx = i; idx < total; idx += stride) out[idx] = 0.0f;
    for (int idx = i; idx < N_NODES; idx += stride) counts[idx] = 0.0f;
}

__global__ void gcn_scatter_kernel(const float* __restrict__ emb,
                                   const int* __restrict__ src,
                                   const int* __restrict__ dst,
                                   float* __restrict__ out,
                                   float* __restrict__ counts) {
    int gid  = blockIdx.x * blockDim.x + threadIdx.x;
    int edge = gid >> 6;
    int lane = gid & 63;
    if (edge >= N_EDGES) return;
    int s = src[edge];
    int d = dst[edge];
    float v = emb[(size_t)s * D_FEAT + lane];
    atomicAdd(&out[(size_t)d * D_FEAT + lane], v);
    if (lane == 0) atomicAdd(&counts[d], 1.0f);
}

__global__ void gcn_norm_kernel(float* __restrict__ out,
                                const float* __restrict__ counts) {
    int i = blockIdx.x * blockDim.x + threadIdx.x;
    if (i >= N_NODES * D_FEAT) return;
    int n = i >> 6;
    float c = counts[n];
    out[i] *= (1.0f / fmaxf(c, 1.0f));
}

// ===========================================================================

extern "C" void kernel_launch(void* const* d_in, const int* in_sizes, int n_in,
                              void* d_out, int out_size, void* d_ws, size_t ws_size,
                              hipStream_t stream) {
    const float* emb = (const float*)d_in[0];
    const int*   src = (const int*)d_in[1];
    const int*   dst = (const int*)d_in[2];
    float* out = (float*)d_out;

    if (ws_size >= WS_NEEDED) {
        int* ws = (int*)d_ws;
        prep_kernel<<<2 * NCHUNK, 1024, 0, stream>>>(emb, src, dst, ws);
        fused_gather_kernel<<<NBINS, 512, 0, stream>>>(ws, out);
    } else {
        float* counts = (float*)d_ws;
        gcn_zero_kernel<<<2048, 256, 0, stream>>>(out, counts);
        const int scatter_blocks = (N_EDGES * 64) / 256;
        gcn_scatter_kernel<<<scatter_blocks, 256, 0, stream>>>(emb, src, dst, out, counts);
        const int norm_blocks = (N_NODES * D_FEAT + 255) / 256;
        gcn_norm_kernel<<<norm_blocks, 256, 0, stream>>>(out, counts);
    }
}